// Round 15
// baseline (116.889 us; speedup 1.0000x reference)
//
#include <hip/hip_runtime.h>
#include <hip/hip_bf16.h>

typedef __bf16 bf16;
typedef __attribute__((ext_vector_type(8))) __bf16 bf16x8;
typedef __attribute__((ext_vector_type(4))) __bf16 bf16x4;
typedef __attribute__((ext_vector_type(4))) float f32x4;

#define NB 2
#define NC 2048
#define NM 1024
#define NH 16
#define NK 64
#define NV 64
#define NHV 1024   // NH*NV

#define MFMA(a, b, c) __builtin_amdgcn_mfma_f32_16x16x32_bf16((a), (b), (c), 0, 0, 0)

// Balanced attn j-table (r14 win): row = CU class (c>>2), col = dispatch wave.
__device__ const unsigned char J8[8][4] = {
  {0, 4, 12, 19},
  {31, 1, 13, 21},
  {30, 2, 14, 20},
  {29, 3, 15, 18},
  {28, 5, 16, 17},
  {27, 6, 11, 22},
  {26, 7, 10, 23},
  {25, 8, 9, 24},
};

// ---------------- fused prep kernel ----------------
__global__ __launch_bounds__(256) void prep_kernel(
    const float* __restrict__ qin, const float* __restrict__ kvin,
    const float* __restrict__ wq, const float* __restrict__ wk,
    const float* __restrict__ wv, const float* __restrict__ wo,
    bf16* __restrict__ qb, bf16* __restrict__ kvb,
    bf16* __restrict__ wqT, bf16* __restrict__ wkT,
    bf16* __restrict__ wvT, bf16* __restrict__ woT) {
  __shared__ float tile[32][33];
  const int bx = blockIdx.x;
  const int tid = threadIdx.x;
  if (bx < 1024) {
    const float4* src = (const float4*)((bx < 512) ? qin : kvin);
    bf16x4* dst = (bf16x4*)((bx < 512) ? qb : kvb);
    int base = (bx & 511) * 2048;
#pragma unroll
    for (int k = 0; k < 8; ++k) {
      int i = base + k * 256 + tid;
      float4 v = src[i];
      bf16x4 o;
      o.x = (bf16)v.x; o.y = (bf16)v.y; o.z = (bf16)v.z; o.w = (bf16)v.w;
      dst[i] = o;
    }
  } else if (bx < 4096) {
    const int sel = (bx >> 10) - 1;  // 0=wq 1=wk 2=wv
    const float* w = (sel == 0) ? wq : (sel == 1) ? wk : wv;
    bf16* wT = (sel == 0) ? wqT : (sel == 1) ? wkT : wvT;
    const int t = bx & 1023;
    const int k0 = (t & 1) * 32, m0 = ((t >> 1) & 31) * 32, h = t >> 6;
    const int tx = tid & 31, ty = tid >> 5;  // 32 x 8
#pragma unroll
    for (int dy = 0; dy < 32; dy += 8)
      tile[ty + dy][tx] = w[((size_t)h * NM + m0 + ty + dy) * NK + k0 + tx];
    __syncthreads();
#pragma unroll
    for (int dy = 0; dy < 32; dy += 8)
      wT[((size_t)h * NK + k0 + ty + dy) * NM + m0 + tx] = (bf16)tile[tx][ty + dy];
  } else {
    const int t = bx & 1023;
    const int hv0 = (t & 31) * 32, m0 = (t >> 5) * 32;
    const int tx = tid & 31, ty = tid >> 5;
#pragma unroll
    for (int dy = 0; dy < 32; dy += 8)
      tile[ty + dy][tx] = wo[((size_t)(hv0 + ty + dy)) * NM + m0 + tx];
    __syncthreads();
#pragma unroll
    for (int dy = 0; dy < 32; dy += 8)
      woT[((size_t)(m0 + ty + dy)) * NHV + hv0 + tx] = (bf16)tile[tx][ty + dy];
  }
}

// ---- fused Q/K/V projections: 128x64 tile, 1536 blocks = 6/CU (TLP for the
// barrier-drain). Grid (x=M/128, y=N/64, z={Q,K,V}); XCD = x%8 pins 4 A-panels.
__global__ __launch_bounds__(256, 6) void proj_fused_kernel(
    const bf16* __restrict__ qb, const bf16* __restrict__ kvb,
    const bf16* __restrict__ wqT, const bf16* __restrict__ wkT,
    const bf16* __restrict__ wvT, bf16* __restrict__ Qp,
    bf16* __restrict__ Kp, bf16* __restrict__ VpT) {
  __shared__ bf16 Al[128 * 64], Bl[64 * 64];
  const int z = blockIdx.z;
  const bf16* Ain = (z == 0) ? qb : kvb;
  const bf16* BTin = (z == 0) ? wqT : (z == 1) ? wkT : wvT;
  const int m0 = blockIdx.x * 128, n0 = blockIdx.y * 64;
  const int tid = threadIdx.x;
  const int w = tid >> 6, lane = tid & 63, lr = lane & 15, lg = lane >> 4;
  const int wm = w >> 1, wn = w & 1;  // wave tile: rows wm*64, cols wn*32
  f32x4 acc[4][2] = {};
  for (int k0 = 0; k0 < 1024; k0 += 64) {
#pragma unroll
    for (int it = 0; it < 4; ++it) {
      int id = it * 256 + tid;
      int row = id >> 3, ch = (id & 7) ^ (row & 7);
      __builtin_amdgcn_global_load_lds(
          (const __attribute__((address_space(1))) void*)(Ain +
              (size_t)(m0 + row) * 1024 + k0 + ch * 8),
          (__attribute__((address_space(3))) void*)&Al[(it * 256 + w * 64) * 8],
          16, 0, 0);
    }
#pragma unroll
    for (int it = 0; it < 2; ++it) {
      int id = it * 256 + tid;
      int row = id >> 3, ch = (id & 7) ^ (row & 7);
      __builtin_amdgcn_global_load_lds(
          (const __attribute__((address_space(1))) void*)(BTin +
              (size_t)(n0 + row) * 1024 + k0 + ch * 8),
          (__attribute__((address_space(3))) void*)&Bl[(it * 256 + w * 64) * 8],
          16, 0, 0);
    }
    __syncthreads();
#pragma unroll
    for (int ks = 0; ks < 2; ++ks) {
      bf16x8 a[4], bb[2];
#pragma unroll
      for (int i = 0; i < 4; ++i) {
        int ra = wm * 64 + i * 16 + lr;
        a[i] = *reinterpret_cast<const bf16x8*>(
            &Al[ra * 64 + (((ks * 4 + lg) ^ (ra & 7)) << 3)]);
      }
#pragma unroll
      for (int i = 0; i < 2; ++i) {
        int rb = wn * 32 + i * 16 + lr;
        bb[i] = *reinterpret_cast<const bf16x8*>(
            &Bl[rb * 64 + (((ks * 4 + lg) ^ (rb & 7)) << 3)]);
      }
#pragma unroll
      for (int mi = 0; mi < 4; ++mi)
#pragma unroll
        for (int ni = 0; ni < 2; ++ni)
          acc[mi][ni] = MFMA(a[mi], bb[ni], acc[mi][ni]);
    }
    __syncthreads();
  }
  if (z < 2) {
    bf16* dst = (z == 0) ? Qp : Kp;
#pragma unroll
    for (int mi = 0; mi < 4; ++mi)
#pragma unroll
      for (int ni = 0; ni < 2; ++ni)
#pragma unroll
        for (int j = 0; j < 4; ++j) {
          int gm = m0 + wm * 64 + mi * 16 + 4 * lg + j;
          int gn = n0 + wn * 32 + ni * 16 + lr;
          dst[(((size_t)((gm >> 11) * 16 + (gn >> 6)) * 2048 + (gm & 2047)) << 6) +
              (gn & 63)] = (bf16)acc[mi][ni][j];
        }
  } else {
#pragma unroll
    for (int mi = 0; mi < 4; ++mi)
#pragma unroll
      for (int ni = 0; ni < 2; ++ni) {
        int gm0 = m0 + wm * 64 + mi * 16 + 4 * lg;
        int gn = n0 + wn * 32 + ni * 16 + lr;
        bf16x4 pv;
#pragma unroll
        for (int j = 0; j < 4; ++j) pv[j] = (bf16)acc[mi][ni][j];
        *reinterpret_cast<bf16x4*>(
            &VpT[((size_t)((gm0 >> 11) * 16 + (gn >> 6)) * 64 + (gn & 63)) * 2048 +
                 (gm0 & 2047)]) = pv;
      }
  }
}

// output GEMM: 64x128 tile, r11 2D grid (64,8)
__global__ __launch_bounds__(256) void out_gemm_kernel(
    const bf16* __restrict__ preb, const bf16* __restrict__ woT,
    float* __restrict__ out) {
  __shared__ bf16 Al[64 * 64], Bl[128 * 64];
  const int m0 = blockIdx.x * 64, n0 = blockIdx.y * 128;
  const int tid = threadIdx.x;
  const int w = tid >> 6, lane = tid & 63, lr = lane & 15, lg = lane >> 4;
  const int wm = w >> 1, wn = w & 1;
  f32x4 acc[2][4] = {};
  for (int k0 = 0; k0 < 1024; k0 += 64) {
#pragma unroll
    for (int it = 0; it < 2; ++it) {
      int id = it * 256 + tid;
      int row = id >> 3, ch = (id & 7) ^ (row & 7);
      __builtin_amdgcn_global_load_lds(
          (const __attribute__((address_space(1))) void*)(preb +
              (size_t)(m0 + row) * 1024 + k0 + ch * 8),
          (__attribute__((address_space(3))) void*)&Al[(it * 256 + w * 64) * 8],
          16, 0, 0);
    }
#pragma unroll
    for (int it = 0; it < 4; ++it) {
      int id = it * 256 + tid;
      int row = id >> 3, ch = (id & 7) ^ (row & 7);
      __builtin_amdgcn_global_load_lds(
          (const __attribute__((address_space(1))) void*)(woT +
              (size_t)(n0 + row) * 1024 + k0 + ch * 8),
          (__attribute__((address_space(3))) void*)&Bl[(it * 256 + w * 64) * 8],
          16, 0, 0);
    }
    __syncthreads();
#pragma unroll
    for (int ks = 0; ks < 2; ++ks) {
      bf16x8 a[2], bb[4];
#pragma unroll
      for (int i = 0; i < 2; ++i) {
        int ra = wm * 32 + i * 16 + lr;
        a[i] = *reinterpret_cast<const bf16x8*>(
            &Al[ra * 64 + (((ks * 4 + lg) ^ (ra & 7)) << 3)]);
      }
#pragma unroll
      for (int i = 0; i < 4; ++i) {
        int rb = wn * 64 + i * 16 + lr;
        bb[i] = *reinterpret_cast<const bf16x8*>(
            &Bl[rb * 64 + (((ks * 4 + lg) ^ (rb & 7)) << 3)]);
      }
#pragma unroll
      for (int mi = 0; mi < 2; ++mi)
#pragma unroll
        for (int ni = 0; ni < 4; ++ni)
          acc[mi][ni] = MFMA(a[mi], bb[ni], acc[mi][ni]);
    }
    __syncthreads();
  }
#pragma unroll
  for (int mi = 0; mi < 2; ++mi)
#pragma unroll
    for (int ni = 0; ni < 4; ++ni)
#pragma unroll
      for (int j = 0; j < 4; ++j) {
        int gm = m0 + wm * 32 + mi * 16 + 4 * lg + j;
        int gn = n0 + wn * 64 + ni * 16 + lr;
        out[(size_t)gm * 1024 + gn] = acc[mi][ni][j];
      }
}

// ---------------- fused attention (r14 exact — measured best) ----------
__global__ __launch_bounds__(256) void attn_kernel(
    const bf16* __restrict__ Qp, const bf16* __restrict__ Kp,
    const bf16* __restrict__ VpT, bf16* __restrict__ preb) {
  __shared__ bf16 Klds[2][64 * 64];
  __shared__ bf16 Vlds[2][64 * 64];
  __shared__ bf16 Plds[4][16 * 64];

  const int g = blockIdx.x;
  const int c = (g >> 3) & 31;           // CU within XCD (round-robin model)
  const int bh = 4 * (g & 7) + (c & 3);  // XCD-local bh group
  const int j = J8[c >> 2][g >> 8];      // balanced q-tile index
  const int b = bh >> 4, h = bh & 15;
  const int tid = threadIdx.x;
  const int w = tid >> 6;
  const int lane = tid & 63;
  const int lr = lane & 15, lg = lane >> 4;
  const int qb0 = j * 64 + w * 16;

  const bf16* Qb = Qp + (size_t)bh * NC * NK;
  const bf16* Kb = Kp + (size_t)bh * NC * NK;
  const bf16* Vb = VpT + (size_t)bh * NV * NC;
  char* PL = (char*)&Plds[w][0];

  bf16x8 qfr[2];
#pragma unroll
  for (int s = 0; s < 2; ++s)
    qfr[s] = *reinterpret_cast<const bf16x8*>(
        Qb + (size_t)(qb0 + lr) * NK + s * 32 + lg * 8);

  f32x4 acc[4] = {};
  float llane = 0.f;

  const float M0 = 8.0f;    // fixed softmax shift
  const float MK = -12.5f;  // mask offset after 1/8 scale

  const int srow = tid >> 3;   // 0..31
  const int sch0 = tid & 7;
  auto STAGE = [&](int buf, int c0) {
#pragma unroll
    for (int i = 0; i < 2; ++i) {
      int row = i * 32 + srow;
      int ch = sch0 ^ (row & 7);
      __builtin_amdgcn_global_load_lds(
          (const __attribute__((address_space(1))) void*)(
              Kb + (size_t)(c0 + row) * NK + ch * 8),
          (__attribute__((address_space(3))) void*)&Klds[buf][(i * 32 + w * 8) * 64],
          16, 0, 0);
      __builtin_amdgcn_global_load_lds(
          (const __attribute__((address_space(1))) void*)(
              Vb + (size_t)row * NC + c0 + ch * 8),
          (__attribute__((address_space(3))) void*)&Vlds[buf][(i * 32 + w * 8) * 64],
          16, 0, 0);
    }
  };

  const int nt = (j == 0) ? (NC / 64) : (j + 1);

  STAGE(0, 0);
  asm volatile("s_waitcnt vmcnt(0)" ::: "memory");
  __syncthreads();

  for (int t = 0; t < nt; ++t) {
    const int cur = t & 1;
    const int c0 = t * 64;
    if (t + 1 < nt) STAGE(cur ^ 1, (t + 1) * 64);

    const char* KL = (const char*)&Klds[cur][0];
    const char* VL = (const char*)&Vlds[cur][0];

    f32x4 S[4] = {};
#pragma unroll
    for (int s = 0; s < 2; ++s)
#pragma unroll
      for (int kf = 0; kf < 4; ++kf) {
        bf16x8 kfr = *reinterpret_cast<const bf16x8*>(
            KL + (kf * 16 + lr) * 128 + (((s * 4 + lg) ^ (lr & 7)) << 4));
        S[kf] = MFMA(kfr, qfr[s], S[kf]);
      }

    {
      const int qg = qb0 + lr;
      bf16x4 pq[4];
      if (t < j) {
#pragma unroll
        for (int kf = 0; kf < 4; ++kf)
#pragma unroll
          for (int i = 0; i < 4; ++i) {
            float p = __expf(fmaf(S[kf][i], 0.125f, -M0));
            llane += p;
            pq[kf][i] = (bf16)p;
          }
      } else if (t == j) {
#pragma unroll
        for (int kf = 0; kf < 4; ++kf)
#pragma unroll
          for (int i = 0; i < 4; ++i) {
            int key = c0 + kf * 16 + 4 * lg + i;
            float off = (key > qg) ? (MK - M0) : -M0;
            float p = __expf(fmaf(S[kf][i], 0.125f, off));
            llane += p;
            pq[kf][i] = (bf16)p;
          }
      } else {  // fully-masked tile (only j==0 blocks reach here)
#pragma unroll
        for (int kf = 0; kf < 4; ++kf)
#pragma unroll
          for (int i = 0; i < 4; ++i) {
            float p = __expf(fmaf(S[kf][i], 0.125f, MK - M0));
            llane += p;
            pq[kf][i] = (bf16)p;
          }
      }
#pragma unroll
      for (int kf = 0; kf < 4; ++kf) {
        int cc = 2 * kf + (lg >> 1);
        *reinterpret_cast<bf16x4*>(
            PL + lr * 128 + ((cc ^ (lr & 7)) << 4) + (lg & 1) * 8) = pq[kf];
      }
    }

#pragma unroll
    for (int s2 = 0; s2 < 2; ++s2) {
      bf16x8 pa = *reinterpret_cast<const bf16x8*>(
          PL + lr * 128 + (((s2 * 4 + lg) ^ (lr & 7)) << 4));
#pragma unroll
      for (int vf = 0; vf < 4; ++vf) {
        bf16x8 vfr = *reinterpret_cast<const bf16x8*>(
            VL + (vf * 16 + lr) * 128 + (((s2 * 4 + lg) ^ (lr & 7)) << 4));
        acc[vf] = MFMA(pa, vfr, acc[vf]);
      }
    }

    asm volatile("s_waitcnt vmcnt(0)" ::: "memory");  // prefetch landed
    __syncthreads();                                   // safe to swap buffers
  }

  llane += __shfl_xor(llane, 16);
  llane += __shfl_xor(llane, 32);
  float li[4];
#pragma unroll
  for (int i = 0; i < 4; ++i) li[i] = 1.0f / __shfl(llane, 4 * lg + i);
  bf16* ob = preb + ((size_t)b * NC) * NHV + (size_t)h * NV;
#pragma unroll
  for (int vf = 0; vf < 4; ++vf)
#pragma unroll
    for (int i = 0; i < 4; ++i) {
      int d = qb0 + 4 * lg + i;
      ob[(size_t)d * NHV + vf * 16 + lr] = (bf16)(acc[vf][i] * li[i]);
    }
}

// ---------------- launch ----------------

extern "C" void kernel_launch(void* const* d_in, const int* in_sizes, int n_in,
                              void* d_out, int out_size, void* d_ws, size_t ws_size,
                              hipStream_t stream) {
  const float* kvinput = (const float*)d_in[0];
  const float* qinput  = (const float*)d_in[1];
  const float* wq = (const float*)d_in[2];
  const float* wk = (const float*)d_in[3];
  const float* wv = (const float*)d_in[4];
  const float* wo = (const float*)d_in[5];
  float* out = (float*)d_out;

  char* ws = (char*)d_ws;
  bf16* qb   = (bf16*)(ws + 0);          //  8,388,608  [NB][NC][NM]
  bf16* kvb  = (bf16*)(ws + 8388608);    //  8,388,608
  bf16* wqT  = (bf16*)(ws + 16777216);   //  2,097,152  [NH][64][NM]
  bf16* wkT  = (bf16*)(ws + 18874368);   //  2,097,152
  bf16* wvT  = (bf16*)(ws + 20971520);   //  2,097,152
  bf16* woT  = (bf16*)(ws + 23068672);   //  2,097,152  [NM][NHV]
  bf16* Qp   = (bf16*)(ws + 25165824);   //  8,388,608  [NB*NH][NC][64]
  bf16* Kp   = (bf16*)(ws + 33554432);   //  8,388,608
  bf16* VpT  = (bf16*)(ws + 41943040);   //  8,388,608  [NB*NH][64][NC]
  bf16* preb = (bf16*)(ws + 50331648);   //  8,388,608  [NB][NC][NHV]

  prep_kernel<<<5120, 256, 0, stream>>>(qinput, kvinput, wq, wk, wv, wo,
                                        qb, kvb, wqT, wkT, wvT, woT);

  dim3 pg(32, 16, 3);  // M/128, N/64, {Q,K,V} — 1536 blocks, 6/CU
  proj_fused_kernel<<<pg, 256, 0, stream>>>(qb, kvb, wqT, wkT, wvT, Qp, Kp, VpT);

  attn_kernel<<<1024, 256, 0, stream>>>(Qp, Kp, VpT, preb);

  dim3 og(64, 8);  // 64x128 tiles (r11 mapping)
  out_gemm_kernel<<<og, 256, 0, stream>>>(preb, woT, out);
}

// Round 16
// 107.728 us; speedup vs baseline: 1.0850x; 1.0850x over previous
//
#include <hip/hip_runtime.h>
#include <hip/hip_bf16.h>

typedef __bf16 bf16;
typedef __attribute__((ext_vector_type(8))) __bf16 bf16x8;
typedef __attribute__((ext_vector_type(4))) __bf16 bf16x4;
typedef __attribute__((ext_vector_type(4))) float f32x4;

#define NB 2
#define NC 2048
#define NM 1024
#define NH 16
#define NK 64
#define NV 64
#define NHV 1024   // NH*NV

#define MFMA(a, b, c) __builtin_amdgcn_mfma_f32_16x16x32_bf16((a), (b), (c), 0, 0, 0)

// Balanced attn j-table (r14 win): row = CU class (c>>2), col = dispatch wave.
__device__ const unsigned char J8[8][4] = {
  {0, 4, 12, 19},
  {31, 1, 13, 21},
  {30, 2, 14, 20},
  {29, 3, 15, 18},
  {28, 5, 16, 17},
  {27, 6, 11, 22},
  {26, 7, 10, 23},
  {25, 8, 9, 24},
};

// ---------------- fused prep kernel ----------------
__global__ __launch_bounds__(256) void prep_kernel(
    const float* __restrict__ qin, const float* __restrict__ kvin,
    const float* __restrict__ wq, const float* __restrict__ wk,
    const float* __restrict__ wv, const float* __restrict__ wo,
    bf16* __restrict__ qb, bf16* __restrict__ kvb,
    bf16* __restrict__ wqT, bf16* __restrict__ wkT,
    bf16* __restrict__ wvT, bf16* __restrict__ woT) {
  __shared__ float tile[32][33];
  const int bx = blockIdx.x;
  const int tid = threadIdx.x;
  if (bx < 1024) {
    const float4* src = (const float4*)((bx < 512) ? qin : kvin);
    bf16x4* dst = (bf16x4*)((bx < 512) ? qb : kvb);
    int base = (bx & 511) * 2048;
#pragma unroll
    for (int k = 0; k < 8; ++k) {
      int i = base + k * 256 + tid;
      float4 v = src[i];
      bf16x4 o;
      o.x = (bf16)v.x; o.y = (bf16)v.y; o.z = (bf16)v.z; o.w = (bf16)v.w;
      dst[i] = o;
    }
  } else if (bx < 4096) {
    const int sel = (bx >> 10) - 1;  // 0=wq 1=wk 2=wv
    const float* w = (sel == 0) ? wq : (sel == 1) ? wk : wv;
    bf16* wT = (sel == 0) ? wqT : (sel == 1) ? wkT : wvT;
    const int t = bx & 1023;
    const int k0 = (t & 1) * 32, m0 = ((t >> 1) & 31) * 32, h = t >> 6;
    const int tx = tid & 31, ty = tid >> 5;  // 32 x 8
#pragma unroll
    for (int dy = 0; dy < 32; dy += 8)
      tile[ty + dy][tx] = w[((size_t)h * NM + m0 + ty + dy) * NK + k0 + tx];
    __syncthreads();
#pragma unroll
    for (int dy = 0; dy < 32; dy += 8)
      wT[((size_t)h * NK + k0 + ty + dy) * NM + m0 + tx] = (bf16)tile[tx][ty + dy];
  } else {
    const int t = bx & 1023;
    const int hv0 = (t & 31) * 32, m0 = (t >> 5) * 32;
    const int tx = tid & 31, ty = tid >> 5;
#pragma unroll
    for (int dy = 0; dy < 32; dy += 8)
      tile[ty + dy][tx] = wo[((size_t)(hv0 + ty + dy)) * NM + m0 + tx];
    __syncthreads();
#pragma unroll
    for (int dy = 0; dy < 32; dy += 8)
      woT[((size_t)(m0 + ty + dy)) * NHV + hv0 + tx] = (bf16)tile[tx][ty + dy];
  }
}

// ---- fused Q/K/V projections: 128x128 tile, BK=64, 2-PHASE double-buffered.
// STAGE(next) issued before compute(cur); one vmcnt(0)+barrier per K-step.
// Grid (x=M/128, y=N/128, z={Q,K,V}); XCD = x%8 pins 4 A-panels per XCD L2.
__global__ __launch_bounds__(256) void proj_fused_kernel(
    const bf16* __restrict__ qb, const bf16* __restrict__ kvb,
    const bf16* __restrict__ wqT, const bf16* __restrict__ wkT,
    const bf16* __restrict__ wvT, bf16* __restrict__ Qp,
    bf16* __restrict__ Kp, bf16* __restrict__ VpT) {
  __shared__ bf16 Al[2][128 * 64], Bl[2][128 * 64];  // 64 KB
  const int z = blockIdx.z;
  const bf16* Ain = (z == 0) ? qb : kvb;
  const bf16* BTin = (z == 0) ? wqT : (z == 1) ? wkT : wvT;
  const int m0 = blockIdx.x * 128, n0 = blockIdx.y * 128;
  const int tid = threadIdx.x;
  const int w = tid >> 6, lane = tid & 63, lr = lane & 15, lg = lane >> 4;
  const int wm = w >> 1, wn = w & 1;
  f32x4 acc[4][4] = {};

  const int srow = tid >> 3;          // 0..31
  const int sch0 = tid & 7;
  auto STAGE = [&](int buf, int k0) {
#pragma unroll
    for (int it = 0; it < 4; ++it) {
      int row = it * 32 + srow;
      int ch = sch0 ^ (row & 7);
      __builtin_amdgcn_global_load_lds(
          (const __attribute__((address_space(1))) void*)(Ain +
              (size_t)(m0 + row) * 1024 + k0 + ch * 8),
          (__attribute__((address_space(3))) void*)&Al[buf][(it * 256 + w * 64) * 8],
          16, 0, 0);
      __builtin_amdgcn_global_load_lds(
          (const __attribute__((address_space(1))) void*)(BTin +
              (size_t)(n0 + row) * 1024 + k0 + ch * 8),
          (__attribute__((address_space(3))) void*)&Bl[buf][(it * 256 + w * 64) * 8],
          16, 0, 0);
    }
  };

  STAGE(0, 0);
  asm volatile("s_waitcnt vmcnt(0)" ::: "memory");
  __syncthreads();

  int cur = 0;
  for (int k0 = 0; k0 < 1024; k0 += 64) {
    if (k0 + 64 < 1024) STAGE(cur ^ 1, k0 + 64);  // prefetch next tile
    const bf16* AL = &Al[cur][0];
    const bf16* BL = &Bl[cur][0];
#pragma unroll
    for (int ks = 0; ks < 2; ++ks) {
      bf16x8 a[4], bb[4];
#pragma unroll
      for (int i = 0; i < 4; ++i) {
        int ra = wm * 64 + i * 16 + lr;
        a[i] = *reinterpret_cast<const bf16x8*>(
            &AL[ra * 64 + (((ks * 4 + lg) ^ (ra & 7)) << 3)]);
        int rb = wn * 64 + i * 16 + lr;
        bb[i] = *reinterpret_cast<const bf16x8*>(
            &BL[rb * 64 + (((ks * 4 + lg) ^ (rb & 7)) << 3)]);
      }
#pragma unroll
      for (int mi = 0; mi < 4; ++mi)
#pragma unroll
        for (int ni = 0; ni < 4; ++ni)
          acc[mi][ni] = MFMA(a[mi], bb[ni], acc[mi][ni]);
    }
    asm volatile("s_waitcnt vmcnt(0)" ::: "memory");  // prefetch landed
    __syncthreads();                                   // all reads of cur done
    cur ^= 1;
  }

  if (z < 2) {
    bf16* dst = (z == 0) ? Qp : Kp;
#pragma unroll
    for (int mi = 0; mi < 4; ++mi)
#pragma unroll
      for (int ni = 0; ni < 4; ++ni)
#pragma unroll
        for (int j = 0; j < 4; ++j) {
          int gm = m0 + wm * 64 + mi * 16 + 4 * lg + j;
          int gn = n0 + wn * 64 + ni * 16 + lr;
          dst[(((size_t)((gm >> 11) * 16 + (gn >> 6)) * 2048 + (gm & 2047)) << 6) +
              (gn & 63)] = (bf16)acc[mi][ni][j];
        }
  } else {
#pragma unroll
    for (int mi = 0; mi < 4; ++mi)
#pragma unroll
      for (int ni = 0; ni < 4; ++ni) {
        int gm0 = m0 + wm * 64 + mi * 16 + 4 * lg;
        int gn = n0 + wn * 64 + ni * 16 + lr;
        bf16x4 pv;
#pragma unroll
        for (int j = 0; j < 4; ++j) pv[j] = (bf16)acc[mi][ni][j];
        *reinterpret_cast<bf16x4*>(
            &VpT[((size_t)((gm0 >> 11) * 16 + (gn >> 6)) * 64 + (gn & 63)) * 2048 +
                 (gm0 & 2047)]) = pv;
      }
  }
}

// output GEMM: 64x128 tile, r11 2D grid (64,8)
__global__ __launch_bounds__(256) void out_gemm_kernel(
    const bf16* __restrict__ preb, const bf16* __restrict__ woT,
    float* __restrict__ out) {
  __shared__ bf16 Al[64 * 64], Bl[128 * 64];
  const int m0 = blockIdx.x * 64, n0 = blockIdx.y * 128;
  const int tid = threadIdx.x;
  const int w = tid >> 6, lane = tid & 63, lr = lane & 15, lg = lane >> 4;
  const int wm = w >> 1, wn = w & 1;
  f32x4 acc[2][4] = {};
  for (int k0 = 0; k0 < 1024; k0 += 64) {
#pragma unroll
    for (int it = 0; it < 2; ++it) {
      int id = it * 256 + tid;
      int row = id >> 3, ch = (id & 7) ^ (row & 7);
      __builtin_amdgcn_global_load_lds(
          (const __attribute__((address_space(1))) void*)(preb +
              (size_t)(m0 + row) * 1024 + k0 + ch * 8),
          (__attribute__((address_space(3))) void*)&Al[(it * 256 + w * 64) * 8],
          16, 0, 0);
    }
#pragma unroll
    for (int it = 0; it < 4; ++it) {
      int id = it * 256 + tid;
      int row = id >> 3, ch = (id & 7) ^ (row & 7);
      __builtin_amdgcn_global_load_lds(
          (const __attribute__((address_space(1))) void*)(woT +
              (size_t)(n0 + row) * 1024 + k0 + ch * 8),
          (__attribute__((address_space(3))) void*)&Bl[(it * 256 + w * 64) * 8],
          16, 0, 0);
    }
    __syncthreads();
#pragma unroll
    for (int ks = 0; ks < 2; ++ks) {
      bf16x8 a[2], bb[4];
#pragma unroll
      for (int i = 0; i < 2; ++i) {
        int ra = wm * 32 + i * 16 + lr;
        a[i] = *reinterpret_cast<const bf16x8*>(
            &Al[ra * 64 + (((ks * 4 + lg) ^ (ra & 7)) << 3)]);
      }
#pragma unroll
      for (int i = 0; i < 4; ++i) {
        int rb = wn * 64 + i * 16 + lr;
        bb[i] = *reinterpret_cast<const bf16x8*>(
            &Bl[rb * 64 + (((ks * 4 + lg) ^ (rb & 7)) << 3)]);
      }
#pragma unroll
      for (int mi = 0; mi < 2; ++mi)
#pragma unroll
        for (int ni = 0; ni < 4; ++ni)
          acc[mi][ni] = MFMA(a[mi], bb[ni], acc[mi][ni]);
    }
    __syncthreads();
  }
#pragma unroll
  for (int mi = 0; mi < 2; ++mi)
#pragma unroll
    for (int ni = 0; ni < 4; ++ni)
#pragma unroll
      for (int j = 0; j < 4; ++j) {
        int gm = m0 + wm * 32 + mi * 16 + 4 * lg + j;
        int gn = n0 + wn * 64 + ni * 16 + lr;
        out[(size_t)gm * 1024 + gn] = acc[mi][ni][j];
      }
}

// ---------------- fused attention (r14 exact — measured best) ----------
__global__ __launch_bounds__(256) void attn_kernel(
    const bf16* __restrict__ Qp, const bf16* __restrict__ Kp,
    const bf16* __restrict__ VpT, bf16* __restrict__ preb) {
  __shared__ bf16 Klds[2][64 * 64];
  __shared__ bf16 Vlds[2][64 * 64];
  __shared__ bf16 Plds[4][16 * 64];

  const int g = blockIdx.x;
  const int c = (g >> 3) & 31;           // CU within XCD (round-robin model)
  const int bh = 4 * (g & 7) + (c & 3);  // XCD-local bh group
  const int j = J8[c >> 2][g >> 8];      // balanced q-tile index
  const int b = bh >> 4, h = bh & 15;
  const int tid = threadIdx.x;
  const int w = tid >> 6;
  const int lane = tid & 63;
  const int lr = lane & 15, lg = lane >> 4;
  const int qb0 = j * 64 + w * 16;

  const bf16* Qb = Qp + (size_t)bh * NC * NK;
  const bf16* Kb = Kp + (size_t)bh * NC * NK;
  const bf16* Vb = VpT + (size_t)bh * NV * NC;
  char* PL = (char*)&Plds[w][0];

  bf16x8 qfr[2];
#pragma unroll
  for (int s = 0; s < 2; ++s)
    qfr[s] = *reinterpret_cast<const bf16x8*>(
        Qb + (size_t)(qb0 + lr) * NK + s * 32 + lg * 8);

  f32x4 acc[4] = {};
  float llane = 0.f;

  const float M0 = 8.0f;    // fixed softmax shift
  const float MK = -12.5f;  // mask offset after 1/8 scale

  const int srow = tid >> 3;   // 0..31
  const int sch0 = tid & 7;
  auto STAGE = [&](int buf, int c0) {
#pragma unroll
    for (int i = 0; i < 2; ++i) {
      int row = i * 32 + srow;
      int ch = sch0 ^ (row & 7);
      __builtin_amdgcn_global_load_lds(
          (const __attribute__((address_space(1))) void*)(
              Kb + (size_t)(c0 + row) * NK + ch * 8),
          (__attribute__((address_space(3))) void*)&Klds[buf][(i * 32 + w * 8) * 64],
          16, 0, 0);
      __builtin_amdgcn_global_load_lds(
          (const __attribute__((address_space(1))) void*)(
              Vb + (size_t)row * NC + c0 + ch * 8),
          (__attribute__((address_space(3))) void*)&Vlds[buf][(i * 32 + w * 8) * 64],
          16, 0, 0);
    }
  };

  const int nt = (j == 0) ? (NC / 64) : (j + 1);

  STAGE(0, 0);
  asm volatile("s_waitcnt vmcnt(0)" ::: "memory");
  __syncthreads();

  for (int t = 0; t < nt; ++t) {
    const int cur = t & 1;
    const int c0 = t * 64;
    if (t + 1 < nt) STAGE(cur ^ 1, (t + 1) * 64);

    const char* KL = (const char*)&Klds[cur][0];
    const char* VL = (const char*)&Vlds[cur][0];

    f32x4 S[4] = {};
#pragma unroll
    for (int s = 0; s < 2; ++s)
#pragma unroll
      for (int kf = 0; kf < 4; ++kf) {
        bf16x8 kfr = *reinterpret_cast<const bf16x8*>(
            KL + (kf * 16 + lr) * 128 + (((s * 4 + lg) ^ (lr & 7)) << 4));
        S[kf] = MFMA(kfr, qfr[s], S[kf]);
      }

    {
      const int qg = qb0 + lr;
      bf16x4 pq[4];
      if (t < j) {
#pragma unroll
        for (int kf = 0; kf < 4; ++kf)
#pragma unroll
          for (int i = 0; i < 4; ++i) {
            float p = __expf(fmaf(S[kf][i], 0.125f, -M0));
            llane += p;
            pq[kf][i] = (bf16)p;
          }
      } else if (t == j) {
#pragma unroll
        for (int kf = 0; kf < 4; ++kf)
#pragma unroll
          for (int i = 0; i < 4; ++i) {
            int key = c0 + kf * 16 + 4 * lg + i;
            float off = (key > qg) ? (MK - M0) : -M0;
            float p = __expf(fmaf(S[kf][i], 0.125f, off));
            llane += p;
            pq[kf][i] = (bf16)p;
          }
      } else {  // fully-masked tile (only j==0 blocks reach here)
#pragma unroll
        for (int kf = 0; kf < 4; ++kf)
#pragma unroll
          for (int i = 0; i < 4; ++i) {
            float p = __expf(fmaf(S[kf][i], 0.125f, MK - M0));
            llane += p;
            pq[kf][i] = (bf16)p;
          }
      }
#pragma unroll
      for (int kf = 0; kf < 4; ++kf) {
        int cc = 2 * kf + (lg >> 1);
        *reinterpret_cast<bf16x4*>(
            PL + lr * 128 + ((cc ^ (lr & 7)) << 4) + (lg & 1) * 8) = pq[kf];
      }
    }

#pragma unroll
    for (int s2 = 0; s2 < 2; ++s2) {
      bf16x8 pa = *reinterpret_cast<const bf16x8*>(
          PL + lr * 128 + (((s2 * 4 + lg) ^ (lr & 7)) << 4));
#pragma unroll
      for (int vf = 0; vf < 4; ++vf) {
        bf16x8 vfr = *reinterpret_cast<const bf16x8*>(
            VL + (vf * 16 + lr) * 128 + (((s2 * 4 + lg) ^ (lr & 7)) << 4));
        acc[vf] = MFMA(pa, vfr, acc[vf]);
      }
    }

    asm volatile("s_waitcnt vmcnt(0)" ::: "memory");  // prefetch landed
    __syncthreads();                                   // safe to swap buffers
  }

  llane += __shfl_xor(llane, 16);
  llane += __shfl_xor(llane, 32);
  float li[4];
#pragma unroll
  for (int i = 0; i < 4; ++i) li[i] = 1.0f / __shfl(llane, 4 * lg + i);
  bf16* ob = preb + ((size_t)b * NC) * NHV + (size_t)h * NV;
#pragma unroll
  for (int vf = 0; vf < 4; ++vf)
#pragma unroll
    for (int i = 0; i < 4; ++i) {
      int d = qb0 + 4 * lg + i;
      ob[(size_t)d * NHV + vf * 16 + lr] = (bf16)(acc[vf][i] * li[i]);
    }
}

// ---------------- launch ----------------

extern "C" void kernel_launch(void* const* d_in, const int* in_sizes, int n_in,
                              void* d_out, int out_size, void* d_ws, size_t ws_size,
                              hipStream_t stream) {
  const float* kvinput = (const float*)d_in[0];
  const float* qinput  = (const float*)d_in[1];
  const float* wq = (const float*)d_in[2];
  const float* wk = (const float*)d_in[3];
  const float* wv = (const float*)d_in[4];
  const float* wo = (const float*)d_in[5];
  float* out = (float*)d_out;

  char* ws = (char*)d_ws;
  bf16* qb   = (bf16*)(ws + 0);          //  8,388,608  [NB][NC][NM]
  bf16* kvb  = (bf16*)(ws + 8388608);    //  8,388,608
  bf16* wqT  = (bf16*)(ws + 16777216);   //  2,097,152  [NH][64][NM]
  bf16* wkT  = (bf16*)(ws + 18874368);   //  2,097,152
  bf16* wvT  = (bf16*)(ws + 20971520);   //  2,097,152
  bf16* woT  = (bf16*)(ws + 23068672);   //  2,097,152  [NM][NHV]
  bf16* Qp   = (bf16*)(ws + 25165824);   //  8,388,608  [NB*NH][NC][64]
  bf16* Kp   = (bf16*)(ws + 33554432);   //  8,388,608
  bf16* VpT  = (bf16*)(ws + 41943040);   //  8,388,608  [NB*NH][64][NC]
  bf16* preb = (bf16*)(ws + 50331648);   //  8,388,608  [NB][NC][NHV]

  prep_kernel<<<5120, 256, 0, stream>>>(qinput, kvinput, wq, wk, wv, wo,
                                        qb, kvb, wqT, wkT, wvT, woT);

  dim3 pg(32, 8, 3);  // M/128, N/128, {Q,K,V} — 2-phase dbuf
  proj_fused_kernel<<<pg, 256, 0, stream>>>(qb, kvb, wqT, wkT, wvT, Qp, Kp, VpT);

  attn_kernel<<<1024, 256, 0, stream>>>(Qp, Kp, VpT, preb);

  dim3 og(64, 8);  // 64x128 tiles (r11 mapping)
  out_gemm_kernel<<<og, 256, 0, stream>>>(preb, woT, out);
}

// Round 17
// 102.012 us; speedup vs baseline: 1.1458x; 1.0560x over previous
//
#include <hip/hip_runtime.h>
#include <hip/hip_bf16.h>

typedef __bf16 bf16;
typedef __attribute__((ext_vector_type(8))) __bf16 bf16x8;
typedef __attribute__((ext_vector_type(4))) __bf16 bf16x4;
typedef __attribute__((ext_vector_type(4))) float f32x4;

#define NB 2
#define NC 2048
#define NM 1024
#define NH 16
#define NK 64
#define NV 64
#define NHV 1024   // NH*NV

#define MFMA(a, b, c) __builtin_amdgcn_mfma_f32_16x16x32_bf16((a), (b), (c), 0, 0, 0)

// Balanced attn j-table (r14 win): row = CU class (c>>2), col = dispatch wave.
__device__ const unsigned char J8[8][4] = {
  {0, 4, 12, 19},
  {31, 1, 13, 21},
  {30, 2, 14, 20},
  {29, 3, 15, 18},
  {28, 5, 16, 17},
  {27, 6, 11, 22},
  {26, 7, 10, 23},
  {25, 8, 9, 24},
};

// ---------------- fused prep kernel ----------------
__global__ __launch_bounds__(256) void prep_kernel(
    const float* __restrict__ qin, const float* __restrict__ kvin,
    const float* __restrict__ wq, const float* __restrict__ wk,
    const float* __restrict__ wv, const float* __restrict__ wo,
    bf16* __restrict__ qb, bf16* __restrict__ kvb,
    bf16* __restrict__ wqT, bf16* __restrict__ wkT,
    bf16* __restrict__ wvT, bf16* __restrict__ woT) {
  __shared__ float tile[32][33];
  const int bx = blockIdx.x;
  const int tid = threadIdx.x;
  if (bx < 1024) {
    const float4* src = (const float4*)((bx < 512) ? qin : kvin);
    bf16x4* dst = (bf16x4*)((bx < 512) ? qb : kvb);
    int base = (bx & 511) * 2048;
#pragma unroll
    for (int k = 0; k < 8; ++k) {
      int i = base + k * 256 + tid;
      float4 v = src[i];
      bf16x4 o;
      o.x = (bf16)v.x; o.y = (bf16)v.y; o.z = (bf16)v.z; o.w = (bf16)v.w;
      dst[i] = o;
    }
  } else if (bx < 4096) {
    const int sel = (bx >> 10) - 1;  // 0=wq 1=wk 2=wv
    const float* w = (sel == 0) ? wq : (sel == 1) ? wk : wv;
    bf16* wT = (sel == 0) ? wqT : (sel == 1) ? wkT : wvT;
    const int t = bx & 1023;
    const int k0 = (t & 1) * 32, m0 = ((t >> 1) & 31) * 32, h = t >> 6;
    const int tx = tid & 31, ty = tid >> 5;  // 32 x 8
#pragma unroll
    for (int dy = 0; dy < 32; dy += 8)
      tile[ty + dy][tx] = w[((size_t)h * NM + m0 + ty + dy) * NK + k0 + tx];
    __syncthreads();
#pragma unroll
    for (int dy = 0; dy < 32; dy += 8)
      wT[((size_t)h * NK + k0 + ty + dy) * NM + m0 + tx] = (bf16)tile[tx][ty + dy];
  } else {
    const int t = bx & 1023;
    const int hv0 = (t & 31) * 32, m0 = (t >> 5) * 32;
    const int tx = tid & 31, ty = tid >> 5;
#pragma unroll
    for (int dy = 0; dy < 32; dy += 8)
      tile[ty + dy][tx] = wo[((size_t)(hv0 + ty + dy)) * NM + m0 + tx];
    __syncthreads();
#pragma unroll
    for (int dy = 0; dy < 32; dy += 8)
      woT[((size_t)(m0 + ty + dy)) * NHV + hv0 + tx] = (bf16)tile[tx][ty + dy];
  }
}

// ---- fused Q/K/V projections: 128x128 tile, BK=64.
// A double-buffered (prefetch fire-and-forget), B single-buffered (staged after
// post-compute barrier; exposed latency hidden by 3-blocks/CU residency).
// LDS 48 KB -> 3 blocks/CU, grid 768 = 3/CU all resident.
// Grid (x=M/128, y=N/128, z={Q,K,V}); XCD = x%8 pins 4 A-panels per XCD L2.
__global__ __launch_bounds__(256) void proj_fused_kernel(
    const bf16* __restrict__ qb, const bf16* __restrict__ kvb,
    const bf16* __restrict__ wqT, const bf16* __restrict__ wkT,
    const bf16* __restrict__ wvT, bf16* __restrict__ Qp,
    bf16* __restrict__ Kp, bf16* __restrict__ VpT) {
  __shared__ bf16 Al[2][128 * 64], Bl[128 * 64];  // 48 KB
  const int z = blockIdx.z;
  const bf16* Ain = (z == 0) ? qb : kvb;
  const bf16* BTin = (z == 0) ? wqT : (z == 1) ? wkT : wvT;
  const int m0 = blockIdx.x * 128, n0 = blockIdx.y * 128;
  const int tid = threadIdx.x;
  const int w = tid >> 6, lane = tid & 63, lr = lane & 15, lg = lane >> 4;
  const int wm = w >> 1, wn = w & 1;
  f32x4 acc[4][4] = {};

  const int srow = tid >> 3;          // 0..31
  const int sch0 = tid & 7;
  auto STAGE_A = [&](int buf, int k0) {
#pragma unroll
    for (int it = 0; it < 4; ++it) {
      int row = it * 32 + srow;
      int ch = sch0 ^ (row & 7);
      __builtin_amdgcn_global_load_lds(
          (const __attribute__((address_space(1))) void*)(Ain +
              (size_t)(m0 + row) * 1024 + k0 + ch * 8),
          (__attribute__((address_space(3))) void*)&Al[buf][(it * 256 + w * 64) * 8],
          16, 0, 0);
    }
  };
  auto STAGE_B = [&](int k0) {
#pragma unroll
    for (int it = 0; it < 4; ++it) {
      int row = it * 32 + srow;
      int ch = sch0 ^ (row & 7);
      __builtin_amdgcn_global_load_lds(
          (const __attribute__((address_space(1))) void*)(BTin +
              (size_t)(n0 + row) * 1024 + k0 + ch * 8),
          (__attribute__((address_space(3))) void*)&Bl[(it * 256 + w * 64) * 8],
          16, 0, 0);
    }
  };

  STAGE_A(0, 0);
  STAGE_B(0);
  asm volatile("s_waitcnt vmcnt(0)" ::: "memory");
  __syncthreads();

  int cur = 0;
  for (int k0 = 0; k0 < 1024; k0 += 64) {
    const bool more = (k0 + 64 < 1024);
    if (more) STAGE_A(cur ^ 1, k0 + 64);  // fire-and-forget into dead A buffer
    const bf16* AL = &Al[cur][0];
#pragma unroll
    for (int ks = 0; ks < 2; ++ks) {
      bf16x8 a[4], bb[4];
#pragma unroll
      for (int i = 0; i < 4; ++i) {
        int ra = wm * 64 + i * 16 + lr;
        a[i] = *reinterpret_cast<const bf16x8*>(
            &AL[ra * 64 + (((ks * 4 + lg) ^ (ra & 7)) << 3)]);
        int rb = wn * 64 + i * 16 + lr;
        bb[i] = *reinterpret_cast<const bf16x8*>(
            &Bl[rb * 64 + (((ks * 4 + lg) ^ (rb & 7)) << 3)]);
      }
#pragma unroll
      for (int mi = 0; mi < 4; ++mi)
#pragma unroll
        for (int ni = 0; ni < 4; ++ni)
          acc[mi][ni] = MFMA(a[mi], bb[ni], acc[mi][ni]);
    }
    __syncthreads();                     // all waves done reading Bl (and Al[cur])
    if (more) STAGE_B(k0 + 64);          // overwrite Bl; latency hidden by TLP
    asm volatile("s_waitcnt vmcnt(0)" ::: "memory");  // A+B prefetch landed
    __syncthreads();
    cur ^= 1;
  }

  if (z < 2) {
    bf16* dst = (z == 0) ? Qp : Kp;
#pragma unroll
    for (int mi = 0; mi < 4; ++mi)
#pragma unroll
      for (int ni = 0; ni < 4; ++ni)
#pragma unroll
        for (int j = 0; j < 4; ++j) {
          int gm = m0 + wm * 64 + mi * 16 + 4 * lg + j;
          int gn = n0 + wn * 64 + ni * 16 + lr;
          dst[(((size_t)((gm >> 11) * 16 + (gn >> 6)) * 2048 + (gm & 2047)) << 6) +
              (gn & 63)] = (bf16)acc[mi][ni][j];
        }
  } else {
#pragma unroll
    for (int mi = 0; mi < 4; ++mi)
#pragma unroll
      for (int ni = 0; ni < 4; ++ni) {
        int gm0 = m0 + wm * 64 + mi * 16 + 4 * lg;
        int gn = n0 + wn * 64 + ni * 16 + lr;
        bf16x4 pv;
#pragma unroll
        for (int j = 0; j < 4; ++j) pv[j] = (bf16)acc[mi][ni][j];
        *reinterpret_cast<bf16x4*>(
            &VpT[((size_t)((gm0 >> 11) * 16 + (gn >> 6)) * 64 + (gn & 63)) * 2048 +
                 (gm0 & 2047)]) = pv;
      }
  }
}

// output GEMM: 64x128 tile, 2-phase dbuf (r16 proj pattern), LDS 48 KB.
// Grid (64,8) = 512 blocks = 2/CU (capacity 3).
__global__ __launch_bounds__(256) void out_gemm_kernel(
    const bf16* __restrict__ preb, const bf16* __restrict__ woT,
    float* __restrict__ out) {
  __shared__ bf16 Al[2][64 * 64], Bl[2][128 * 64];  // 16 + 32 KB
  const int m0 = blockIdx.x * 64, n0 = blockIdx.y * 128;
  const int tid = threadIdx.x;
  const int w = tid >> 6, lane = tid & 63, lr = lane & 15, lg = lane >> 4;
  const int wm = w >> 1, wn = w & 1;
  f32x4 acc[2][4] = {};

  auto STAGE = [&](int buf, int k0) {
#pragma unroll
    for (int it = 0; it < 2; ++it) {
      int id = it * 256 + tid;
      int row = id >> 3, ch = (id & 7) ^ (row & 7);
      __builtin_amdgcn_global_load_lds(
          (const __attribute__((address_space(1))) void*)(preb +
              (size_t)(m0 + row) * 1024 + k0 + ch * 8),
          (__attribute__((address_space(3))) void*)&Al[buf][(it * 256 + w * 64) * 8],
          16, 0, 0);
    }
#pragma unroll
    for (int it = 0; it < 4; ++it) {
      int id = it * 256 + tid;
      int row = id >> 3, ch = (id & 7) ^ (row & 7);
      __builtin_amdgcn_global_load_lds(
          (const __attribute__((address_space(1))) void*)(woT +
              (size_t)(n0 + row) * 1024 + k0 + ch * 8),
          (__attribute__((address_space(3))) void*)&Bl[buf][(it * 256 + w * 64) * 8],
          16, 0, 0);
    }
  };

  STAGE(0, 0);
  asm volatile("s_waitcnt vmcnt(0)" ::: "memory");
  __syncthreads();

  int cur = 0;
  for (int k0 = 0; k0 < 1024; k0 += 64) {
    if (k0 + 64 < 1024) STAGE(cur ^ 1, k0 + 64);
    const bf16* AL = &Al[cur][0];
    const bf16* BL = &Bl[cur][0];
#pragma unroll
    for (int ks = 0; ks < 2; ++ks) {
      bf16x8 a[2], bb[4];
#pragma unroll
      for (int i = 0; i < 2; ++i) {
        int ra = wm * 32 + i * 16 + lr;
        a[i] = *reinterpret_cast<const bf16x8*>(
            &AL[ra * 64 + (((ks * 4 + lg) ^ (ra & 7)) << 3)]);
      }
#pragma unroll
      for (int i = 0; i < 4; ++i) {
        int rb = wn * 64 + i * 16 + lr;
        bb[i] = *reinterpret_cast<const bf16x8*>(
            &BL[rb * 64 + (((ks * 4 + lg) ^ (rb & 7)) << 3)]);
      }
#pragma unroll
      for (int mi = 0; mi < 2; ++mi)
#pragma unroll
        for (int ni = 0; ni < 4; ++ni)
          acc[mi][ni] = MFMA(a[mi], bb[ni], acc[mi][ni]);
    }
    asm volatile("s_waitcnt vmcnt(0)" ::: "memory");
    __syncthreads();
    cur ^= 1;
  }
#pragma unroll
  for (int mi = 0; mi < 2; ++mi)
#pragma unroll
    for (int ni = 0; ni < 4; ++ni)
#pragma unroll
      for (int j = 0; j < 4; ++j) {
        int gm = m0 + wm * 32 + mi * 16 + 4 * lg + j;
        int gn = n0 + wn * 64 + ni * 16 + lr;
        out[(size_t)gm * 1024 + gn] = acc[mi][ni][j];
      }
}

// ---------------- fused attention (r14/r16 exact — measured best) ----------
__global__ __launch_bounds__(256) void attn_kernel(
    const bf16* __restrict__ Qp, const bf16* __restrict__ Kp,
    const bf16* __restrict__ VpT, bf16* __restrict__ preb) {
  __shared__ bf16 Klds[2][64 * 64];
  __shared__ bf16 Vlds[2][64 * 64];
  __shared__ bf16 Plds[4][16 * 64];

  const int g = blockIdx.x;
  const int c = (g >> 3) & 31;           // CU within XCD (round-robin model)
  const int bh = 4 * (g & 7) + (c & 3);  // XCD-local bh group
  const int j = J8[c >> 2][g >> 8];      // balanced q-tile index
  const int b = bh >> 4, h = bh & 15;
  const int tid = threadIdx.x;
  const int w = tid >> 6;
  const int lane = tid & 63;
  const int lr = lane & 15, lg = lane >> 4;
  const int qb0 = j * 64 + w * 16;

  const bf16* Qb = Qp + (size_t)bh * NC * NK;
  const bf16* Kb = Kp + (size_t)bh * NC * NK;
  const bf16* Vb = VpT + (size_t)bh * NV * NC;
  char* PL = (char*)&Plds[w][0];

  bf16x8 qfr[2];
#pragma unroll
  for (int s = 0; s < 2; ++s)
    qfr[s] = *reinterpret_cast<const bf16x8*>(
        Qb + (size_t)(qb0 + lr) * NK + s * 32 + lg * 8);

  f32x4 acc[4] = {};
  float llane = 0.f;

  const float M0 = 8.0f;    // fixed softmax shift
  const float MK = -12.5f;  // mask offset after 1/8 scale

  const int srow = tid >> 3;   // 0..31
  const int sch0 = tid & 7;
  auto STAGE = [&](int buf, int c0) {
#pragma unroll
    for (int i = 0; i < 2; ++i) {
      int row = i * 32 + srow;
      int ch = sch0 ^ (row & 7);
      __builtin_amdgcn_global_load_lds(
          (const __attribute__((address_space(1))) void*)(
              Kb + (size_t)(c0 + row) * NK + ch * 8),
          (__attribute__((address_space(3))) void*)&Klds[buf][(i * 32 + w * 8) * 64],
          16, 0, 0);
      __builtin_amdgcn_global_load_lds(
          (const __attribute__((address_space(1))) void*)(
              Vb + (size_t)row * NC + c0 + ch * 8),
          (__attribute__((address_space(3))) void*)&Vlds[buf][(i * 32 + w * 8) * 64],
          16, 0, 0);
    }
  };

  const int nt = (j == 0) ? (NC / 64) : (j + 1);

  STAGE(0, 0);
  asm volatile("s_waitcnt vmcnt(0)" ::: "memory");
  __syncthreads();

  for (int t = 0; t < nt; ++t) {
    const int cur = t & 1;
    const int c0 = t * 64;
    if (t + 1 < nt) STAGE(cur ^ 1, (t + 1) * 64);

    const char* KL = (const char*)&Klds[cur][0];
    const char* VL = (const char*)&Vlds[cur][0];

    f32x4 S[4] = {};
#pragma unroll
    for (int s = 0; s < 2; ++s)
#pragma unroll
      for (int kf = 0; kf < 4; ++kf) {
        bf16x8 kfr = *reinterpret_cast<const bf16x8*>(
            KL + (kf * 16 + lr) * 128 + (((s * 4 + lg) ^ (lr & 7)) << 4));
        S[kf] = MFMA(kfr, qfr[s], S[kf]);
      }

    {
      const int qg = qb0 + lr;
      bf16x4 pq[4];
      if (t < j) {
#pragma unroll
        for (int kf = 0; kf < 4; ++kf)
#pragma unroll
          for (int i = 0; i < 4; ++i) {
            float p = __expf(fmaf(S[kf][i], 0.125f, -M0));
            llane += p;
            pq[kf][i] = (bf16)p;
          }
      } else if (t == j) {
#pragma unroll
        for (int kf = 0; kf < 4; ++kf)
#pragma unroll
          for (int i = 0; i < 4; ++i) {
            int key = c0 + kf * 16 + 4 * lg + i;
            float off = (key > qg) ? (MK - M0) : -M0;
            float p = __expf(fmaf(S[kf][i], 0.125f, off));
            llane += p;
            pq[kf][i] = (bf16)p;
          }
      } else {  // fully-masked tile (only j==0 blocks reach here)
#pragma unroll
        for (int kf = 0; kf < 4; ++kf)
#pragma unroll
          for (int i = 0; i < 4; ++i) {
            float p = __expf(fmaf(S[kf][i], 0.125f, MK - M0));
            llane += p;
            pq[kf][i] = (bf16)p;
          }
      }
#pragma unroll
      for (int kf = 0; kf < 4; ++kf) {
        int cc = 2 * kf + (lg >> 1);
        *reinterpret_cast<bf16x4*>(
            PL + lr * 128 + ((cc ^ (lr & 7)) << 4) + (lg & 1) * 8) = pq[kf];
      }
    }

#pragma unroll
    for (int s2 = 0; s2 < 2; ++s2) {
      bf16x8 pa = *reinterpret_cast<const bf16x8*>(
          PL + lr * 128 + (((s2 * 4 + lg) ^ (lr & 7)) << 4));
#pragma unroll
      for (int vf = 0; vf < 4; ++vf) {
        bf16x8 vfr = *reinterpret_cast<const bf16x8*>(
            VL + (vf * 16 + lr) * 128 + (((s2 * 4 + lg) ^ (lr & 7)) << 4));
        acc[vf] = MFMA(pa, vfr, acc[vf]);
      }
    }

    asm volatile("s_waitcnt vmcnt(0)" ::: "memory");  // prefetch landed
    __syncthreads();                                   // safe to swap buffers
  }

  llane += __shfl_xor(llane, 16);
  llane += __shfl_xor(llane, 32);
  float li[4];
#pragma unroll
  for (int i = 0; i < 4; ++i) li[i] = 1.0f / __shfl(llane, 4 * lg + i);
  bf16* ob = preb + ((size_t)b * NC) * NHV + (size_t)h * NV;
#pragma unroll
  for (int vf = 0; vf < 4; ++vf)
#pragma unroll
    for (int i = 0; i < 4; ++i) {
      int d = qb0 + 4 * lg + i;
      ob[(size_t)d * NHV + vf * 16 + lr] = (bf16)(acc[vf][i] * li[i]);
    }
}

// ---------------- launch ----------------

extern "C" void kernel_launch(void* const* d_in, const int* in_sizes, int n_in,
                              void* d_out, int out_size, void* d_ws, size_t ws_size,
                              hipStream_t stream) {
  const float* kvinput = (const float*)d_in[0];
  const float* qinput  = (const float*)d_in[1];
  const float* wq = (const float*)d_in[2];
  const float* wk = (const float*)d_in[3];
  const float* wv = (const float*)d_in[4];
  const float* wo = (const float*)d_in[5];
  float* out = (float*)d_out;

  char* ws = (char*)d_ws;
  bf16* qb   = (bf16*)(ws + 0);          //  8,388,608  [NB][NC][NM]
  bf16* kvb  = (bf16*)(ws + 8388608);    //  8,388,608
  bf16* wqT  = (bf16*)(ws + 16777216);   //  2,097,152  [NH][64][NM]
  bf16* wkT  = (bf16*)(ws + 18874368);   //  2,097,152
  bf16* wvT  = (bf16*)(ws + 20971520);   //  2,097,152
  bf16* woT  = (bf16*)(ws + 23068672);   //  2,097,152  [NM][NHV]
  bf16* Qp   = (bf16*)(ws + 25165824);   //  8,388,608  [NB*NH][NC][64]
  bf16* Kp   = (bf16*)(ws + 33554432);   //  8,388,608
  bf16* VpT  = (bf16*)(ws + 41943040);   //  8,388,608  [NB*NH][64][NC]
  bf16* preb = (bf16*)(ws + 50331648);   //  8,388,608  [NB][NC][NHV]

  prep_kernel<<<5120, 256, 0, stream>>>(qinput, kvinput, wq, wk, wv, wo,
                                        qb, kvb, wqT, wkT, wvT, woT);

  dim3 pg(32, 8, 3);  // M/128, N/128, {Q,K,V} — A-dbuf/B-single, 3 blocks/CU
  proj_fused_kernel<<<pg, 256, 0, stream>>>(qb, kvb, wqT, wkT, wvT, Qp, Kp, VpT);

  attn_kernel<<<1024, 256, 0, stream>>>(Qp, Kp, VpT, preb);

  dim3 og(64, 8);  // 64x128 tiles, 2-phase dbuf
  out_gemm_kernel<<<og, 256, 0, stream>>>(preb, woT, out);
}